// Round 6
// baseline (381.569 us; speedup 1.0000x reference)
//
#include <hip/hip_runtime.h>
#include <stdint.h>

typedef unsigned short ushort_t;
typedef _Float16 f16;
typedef __attribute__((ext_vector_type(8))) _Float16 half8;
typedef __attribute__((ext_vector_type(4))) _Float16 half4;
typedef __attribute__((ext_vector_type(4))) float float4v;

#define AS1 __attribute__((address_space(1)))
#define AS3 __attribute__((address_space(3)))

// async global->LDS, 16B per lane (global_load_lds_dwordx4)
static __device__ __forceinline__ void gload16(const void* g, void* l) {
    __builtin_amdgcn_global_load_lds((const AS1 unsigned int*)g,
                                     (AS3 unsigned int*)l, 16, 0, 0);
}

// ---------------------------------------------------------------------
// fp16 MFMA GEMM, flatmm-style: A staged to LDS (128x64 per iter, 16 KiB),
// B streamed global->VGPR fragments with one-half-tile prefetch (its L2
// latency hides under MFMAs / the staging barrier drain). LDS reads per
// half-step drop 8->4 ds_read_b128 (~48 cyc) < 16 MFMA (~74 cyc): the
// inner loop becomes MFMA-bound instead of LDS-bound.
// A: [M, K] rows stride lda (fp16); B: [N, K] rows stride ldb (fp16)
// C = A*B^T (+bias[n])
// OUT: 0 = fp32 at Cf[z*zsC + row*ldc + col]
//      1 = f16  at Ch[z*zsC + row*ldc + col]
//      4 = fused QKV: col<2048 -> f16 qk[row*2048+col];
//          col>=2048 -> f16 V^T packed: Vt[(row>>11)*1024 + col-2048][row&2047]
// ---------------------------------------------------------------------
template<int OUT, bool BIAS>
__global__ __launch_bounds__(256)
void gemm_k(const f16* __restrict__ A, const f16* __restrict__ B,
            const float* __restrict__ bias,
            float* __restrict__ Cf, f16* __restrict__ Ch, f16* __restrict__ Vt,
            int K, int lda, int ldb, int ldc,
            long zsA, long zsB, long zsC)
{
    extern __shared__ f16 smem[];
    f16* sA0 = smem;            // 128x32
    f16* sA1 = smem + 4096;     // 128x32  -> 16 KiB total

    const long zb = blockIdx.z;
    A += zb * zsA; B += zb * zsB;

    const int t  = threadIdx.x;
    const int bm = blockIdx.x * 128;
    const int bn = blockIdx.y * 128;

    const int  srow = t >> 2;
    const int  skg  = (t & 3) * 8;
    const f16* gA = A + (long)(bm + srow) * lda + skg;
    const long rstepA = (long)64 * lda;

    const int lane = t & 63;
    const int wv   = t >> 6;
    const int wm   = (wv & 1) * 64;
    const int wn   = (wv >> 1) * 64;
    const int lm   = lane & 15;
    const int q    = lane >> 4;

    // B fragment base: lane lm covers row bn+wn+j*16+lm, quad q covers 8 k
    const f16* Bb = B + (long)(bn + wn + lm) * ldb + q * 8;
    const long jstep = (long)16 * ldb;

    float4v acc[4][4];
    #pragma unroll
    for (int i = 0; i < 4; ++i)
        #pragma unroll
        for (int j = 0; j < 4; ++j)
            #pragma unroll
            for (int r = 0; r < 4; ++r) acc[i][j][r] = 0.f;

    half8 b0[4], b1[4];
    #pragma unroll
    for (int j = 0; j < 4; ++j) b0[j] = *(const half8*)(Bb + j * jstep);

    for (int kt = 0; kt < K; kt += 64) {
        __syncthreads();
        #pragma unroll
        for (int r = 0; r < 2; ++r) {
            gload16(gA + kt      + r * rstepA, sA0 + r * 2048 + t * 8);
            gload16(gA + kt + 32 + r * rstepA, sA1 + r * 2048 + t * 8);
        }
        // prefetch ks=1 fragments; arrival guaranteed by the barrier drain
        #pragma unroll
        for (int j = 0; j < 4; ++j) b1[j] = *(const half8*)(Bb + j * jstep + kt + 32);
        __syncthreads();

        half8 a[4];
        #pragma unroll
        for (int i = 0; i < 4; ++i)
            a[i] = *(const half8*)(sA0 + (wm + i * 16 + lm) * 32 + q * 8);
        #pragma unroll
        for (int i = 0; i < 4; ++i)
            #pragma unroll
            for (int j = 0; j < 4; ++j)
                acc[i][j] = __builtin_amdgcn_mfma_f32_16x16x32_f16(a[i], b0[j], acc[i][j], 0, 0, 0);

        // prefetch next kt's ks=0 fragments (fly across the next barrier)
        const int ktn = (kt + 64 < K) ? kt + 64 : 0;
        #pragma unroll
        for (int j = 0; j < 4; ++j) b0[j] = *(const half8*)(Bb + j * jstep + ktn);

        #pragma unroll
        for (int i = 0; i < 4; ++i)
            a[i] = *(const half8*)(sA1 + (wm + i * 16 + lm) * 32 + q * 8);
        #pragma unroll
        for (int i = 0; i < 4; ++i)
            #pragma unroll
            for (int j = 0; j < 4; ++j)
                acc[i][j] = __builtin_amdgcn_mfma_f32_16x16x32_f16(a[i], b1[j], acc[i][j], 0, 0, 0);
    }

    // epilogue; C/D layout: col = lane&15, row = (lane>>4)*4 + reg (m89/m91)
    #pragma unroll
    for (int i = 0; i < 4; ++i) {
        const int rowb = bm + wm + i * 16 + q * 4;
        #pragma unroll
        for (int j = 0; j < 4; ++j) {
            const int col = bn + wn + j * 16 + lm;
            const float bv_ = BIAS ? bias[col] : 0.f;
            if (OUT == 4 && col >= 2048) {
                // packed V^T store: 4 consecutive s-positions -> one 8B store
                half4 pk;
                #pragma unroll
                for (int r = 0; r < 4; ++r) pk[r] = (f16)(acc[i][j][r] + bv_);
                *(half4*)(Vt + ((long)(rowb >> 11) * 1024 + (col - 2048)) * 2048 + (rowb & 2047)) = pk;
            } else {
                #pragma unroll
                for (int r = 0; r < 4; ++r) {
                    const float val = acc[i][j][r] + bv_;
                    const int row = rowb + r;
                    if (OUT == 0)      Cf[zb * zsC + (long)row * ldc + col] = val;
                    else if (OUT == 1) Ch[zb * zsC + (long)row * ldc + col] = (f16)val;
                    else               Ch[(long)row * ldc + col] = (f16)val;
                }
            }
        }
    }
}

// ---------------------------------------------------------------------
// fused preprocessing, one dispatch:
//  blocks [0,8192):    x fp32 -> fp16
//  blocks [8192,8960): Wq/Wk/Wv [1024,1024] fp32 -> W^T fp16 [3072,1024]
//  blocks [8960,8972): bias concat -> bqkv[3072]
// ---------------------------------------------------------------------
__global__ __launch_bounds__(256)
void preproc_k(const float* __restrict__ x,
               const float* __restrict__ Wq, const float* __restrict__ Wk,
               const float* __restrict__ Wv,
               const float* __restrict__ bq, const float* __restrict__ bk,
               const float* __restrict__ bv,
               f16* __restrict__ xh, f16* __restrict__ WT, float* __restrict__ bqkv)
{
    __shared__ float tile[64][65];
    const int bx = blockIdx.x;
    const int t  = threadIdx.x;

    if (bx < 8192) {
        const long i = ((long)bx * 256 + t) * 4;
        const float4v v = *(const float4v*)(x + i);
        half4 h;
        #pragma unroll
        for (int j = 0; j < 4; ++j) h[j] = (f16)v[j];
        *(half4*)(xh + i) = h;
    } else if (bx < 8960) {
        const int f = bx - 8192;
        const int z = f >> 8;
        const int rem = f & 255;
        const int n0 = (rem & 15) * 64;
        const int k0 = (rem >> 4) * 64;
        const float* W = (z == 0) ? Wq : (z == 1) ? Wk : Wv;
        f16* T = WT + (long)z * 1048576;
        #pragma unroll
        for (int i = 0; i < 4; ++i) {
            const int r = (t >> 4) + i * 16;     // k local
            const int c = (t & 15) * 4;          // n local
            const float4v v = *(const float4v*)(W + (long)(k0 + r) * 1024 + n0 + c);
            tile[r][c + 0] = v[0]; tile[r][c + 1] = v[1];
            tile[r][c + 2] = v[2]; tile[r][c + 3] = v[3];
        }
        __syncthreads();
        #pragma unroll
        for (int i = 0; i < 4; ++i) {
            const int nr = (t >> 4) + i * 16;    // n local
            const int c  = (t & 15) * 4;         // k local
            half4 h;
            #pragma unroll
            for (int j = 0; j < 4; ++j) h[j] = (f16)tile[c + j][nr];
            *(half4*)(T + (long)(n0 + nr) * 1024 + k0 + c) = h;
        }
    } else {
        const int i = (bx - 8960) * 256 + t;
        bqkv[i] = (i < 1024) ? bq[i] : (i < 2048) ? bk[i - 1024] : bv[i - 2048];
    }
}

// ---- row softmax, in place: f16 [rows, 2048] ----
__global__ __launch_bounds__(256)
void softmax_k(f16* __restrict__ Sc)
{
    const int t = threadIdx.x;
    const long row = blockIdx.x;
    half8* p = (half8*)(Sc + row * 2048);
    const half8 hv = p[t];
    float xv[8];
    #pragma unroll
    for (int j = 0; j < 8; ++j) xv[j] = (float)hv[j];

    float m = -1e30f;
    #pragma unroll
    for (int j = 0; j < 8; ++j) m = fmaxf(m, xv[j]);
    #pragma unroll
    for (int off = 32; off; off >>= 1) m = fmaxf(m, __shfl_xor(m, off, 64));
    __shared__ float r1[4], r2[4];
    if ((t & 63) == 0) r1[t >> 6] = m;
    __syncthreads();
    m = fmaxf(fmaxf(r1[0], r1[1]), fmaxf(r1[2], r1[3]));

    float s = 0.f;
    #pragma unroll
    for (int j = 0; j < 8; ++j) { xv[j] = __expf(xv[j] - m); s += xv[j]; }
    #pragma unroll
    for (int off = 32; off; off >>= 1) s += __shfl_xor(s, off, 64);
    if ((t & 63) == 0) r2[t >> 6] = s;
    __syncthreads();
    s = r2[0] + r2[1] + r2[2] + r2[3];
    const float inv = 1.f / s;

    half8 o;
    #pragma unroll
    for (int j = 0; j < 8; ++j) o[j] = (f16)(xv[j] * inv);
    p[t] = o;
}

// ---------------------------------------------------------------------
extern "C" void kernel_launch(void* const* d_in, const int* in_sizes, int n_in,
                              void* d_out, int out_size, void* d_ws, size_t ws_size,
                              hipStream_t stream)
{
    const float* x  = (const float*)d_in[0];
    const float* Wq = (const float*)d_in[1];
    const float* bq = (const float*)d_in[2];
    const float* Wk = (const float*)d_in[3];
    const float* bk = (const float*)d_in[4];
    const float* Wv = (const float*)d_in[5];
    const float* bv = (const float*)d_in[6];
    float* out = (float*)d_out;

    char* ws = (char*)d_ws;
    const long MiB = 1024 * 1024;
    // Phase-1 temporaries (dead once the projection finishes)
    f16*   xh   = (f16*)  (ws + 0);          // 16 MiB [8192,1024]
    f16*   WT   = (f16*)  (ws + 16 * MiB);   //  6 MiB [3072,1024]
    float* bqkv = (float*)(ws + 22 * MiB);   // 12 KiB
    // Persistent / attention-phase
    f16*   scores = (f16*) (ws + 0);         // 32 MiB [4][2048][2048] f16, in-place softmax
    f16*   qk     = (f16*) (ws + 64 * MiB);  // 32 MiB [8192,2048] (q cols 0..1023, k cols 1024..2047)
    f16*   vT     = (f16*) (ws + 96 * MiB);  // 16 MiB [4][1024][2048]  -> total 112 MiB

    // 1) fused preprocessing (1 dispatch)
    preproc_k<<<8972, 256, 0, stream>>>(x, Wq, Wk, Wv, bq, bk, bv, xh, WT, bqkv);

    // 2) fused QKV projection (fp16), V^T written directly
    gemm_k<4, true><<<dim3(64, 24, 1), 256, 16384, stream>>>(
        xh, WT, bqkv, nullptr, qk, vT,
        1024, 1024, 1024, 2048, 0, 0, 0);

    // 3) attention: scores = QK^T (f16), in-place softmax, out = P V
    const long SS = (long)2048 * 2048;
    gemm_k<1, false><<<dim3(16, 16, 4), 256, 16384, stream>>>(
        qk, qk + 1024, nullptr, nullptr, scores, nullptr,
        1024, 2048, 2048, 2048, SS, SS, SS);
    softmax_k<<<8192, 256, 0, stream>>>(scores);
    gemm_k<0, false><<<dim3(16, 8, 4), 256, 16384, stream>>>(
        scores, vT, nullptr, out, nullptr, nullptr,
        2048, 2048, 2048, 1024, SS, (long)1024 * 2048, (long)2048 * 1024);
}

// Round 7
// 264.100 us; speedup vs baseline: 1.4448x; 1.4448x over previous
//
#include <hip/hip_runtime.h>
#include <stdint.h>

typedef unsigned short ushort_t;
typedef _Float16 f16;
typedef __attribute__((ext_vector_type(8))) _Float16 half8;
typedef __attribute__((ext_vector_type(4))) _Float16 half4;
typedef __attribute__((ext_vector_type(4))) float float4v;

#define AS1 __attribute__((address_space(1)))
#define AS3 __attribute__((address_space(3)))

// async global->LDS, 16B per lane (global_load_lds_dwordx4)
static __device__ __forceinline__ void gload16(const void* g, void* l) {
    __builtin_amdgcn_global_load_lds((const AS1 unsigned int*)g,
                                     (AS3 unsigned int*)l, 16, 0, 0);
}

// ---------------------------------------------------------------------
// fp16 MFMA GEMM, both operands LDS-staged (r5 structure), BK=64 via two
// 32-wide sub-tiles (keeps conflict-free layout + lane-contiguous
// global_load_lds). Wave tile IM*16 x 64; block tile (2*IM*16) x 128.
// IM=8: 12 ds_read_b128 serve 32 MFMAs per half-step (vs 8/16 at IM=4)
// -> 25% less LDS traffic per MFMA, half the B staging.
// A: [M, K] rows stride lda (fp16); B: [N, K] rows stride ldb (fp16)
// C = A*B^T (+bias[n])
// OUT: 0 = fp32 at Cf[z*zsC + row*ldc + col]
//      1 = f16  at Ch[z*zsC + row*ldc + col]
//      4 = fused QKV: col<2048 -> f16 qk[row*2048+col];
//          col>=2048 -> f16 V^T packed: Vt[(row>>11)*1024 + col-2048][row&2047]
// ---------------------------------------------------------------------
template<int IM, int OUT, bool BIAS>
__global__ __launch_bounds__(256, IM == 8 ? 2 : 4)
void gemm_k(const f16* __restrict__ A, const f16* __restrict__ B,
            const float* __restrict__ bias,
            float* __restrict__ Cf, f16* __restrict__ Ch, f16* __restrict__ Vt,
            int K, int lda, int ldb, int ldc,
            long zsA, long zsB, long zsC)
{
    constexpr int R = IM * 32;            // block m rows (128 or 256)
    extern __shared__ f16 smem[];
    f16* sA0 = smem;                      // R x 32
    f16* sA1 = smem + R * 32;             // R x 32
    f16* sB0 = smem + 2 * R * 32;         // 128 x 32
    f16* sB1 = sB0 + 4096;                // 128 x 32

    const long zb = blockIdx.z;
    A += zb * zsA; B += zb * zsB;

    const int t  = threadIdx.x;
    const int bm = blockIdx.x * R;
    const int bn = blockIdx.y * 128;

    const int  srow = t >> 2;
    const int  skg  = (t & 3) * 8;
    const f16* gA = A + (long)(bm + srow) * lda + skg;
    const f16* gB = B + (long)(bn + srow) * ldb + skg;
    const long rstepA = (long)64 * lda;
    const long rstepB = (long)64 * ldb;

    const int lane = t & 63;
    const int wv   = t >> 6;
    const int wm   = (wv & 1) * (IM * 16);
    const int wn   = (wv >> 1) * 64;
    const int lm   = lane & 15;
    const int q    = lane >> 4;

    float4v acc[IM][4];
    #pragma unroll
    for (int i = 0; i < IM; ++i)
        #pragma unroll
        for (int j = 0; j < 4; ++j)
            #pragma unroll
            for (int r = 0; r < 4; ++r) acc[i][j][r] = 0.f;

    for (int kt = 0; kt < K; kt += 64) {
        __syncthreads();
        #pragma unroll
        for (int r = 0; r < R / 64; ++r) {
            gload16(gA + kt      + r * rstepA, sA0 + r * 2048 + t * 8);
            gload16(gA + kt + 32 + r * rstepA, sA1 + r * 2048 + t * 8);
        }
        #pragma unroll
        for (int r = 0; r < 2; ++r) {
            gload16(gB + kt      + r * rstepB, sB0 + r * 2048 + t * 8);
            gload16(gB + kt + 32 + r * rstepB, sB1 + r * 2048 + t * 8);
        }
        __syncthreads();

        #pragma unroll
        for (int ks = 0; ks < 2; ++ks) {
            const f16* sA = ks ? sA1 : sA0;
            const f16* sB = ks ? sB1 : sB0;
            half8 a[IM], b[4];
            #pragma unroll
            for (int i = 0; i < IM; ++i)
                a[i] = *(const half8*)(sA + (wm + i * 16 + lm) * 32 + q * 8);
            #pragma unroll
            for (int j = 0; j < 4; ++j)
                b[j] = *(const half8*)(sB + (wn + j * 16 + lm) * 32 + q * 8);
            #pragma unroll
            for (int i = 0; i < IM; ++i)
                #pragma unroll
                for (int j = 0; j < 4; ++j)
                    acc[i][j] = __builtin_amdgcn_mfma_f32_16x16x32_f16(a[i], b[j], acc[i][j], 0, 0, 0);
        }
    }

    // epilogue; C/D layout: col = lane&15, row = (lane>>4)*4 + reg (m89/m91)
    #pragma unroll
    for (int i = 0; i < IM; ++i) {
        const int rowb = bm + wm + i * 16 + q * 4;
        #pragma unroll
        for (int j = 0; j < 4; ++j) {
            const int col = bn + wn + j * 16 + lm;
            const float bv_ = BIAS ? bias[col] : 0.f;
            if (OUT == 4 && col >= 2048) {
                // packed V^T store: 4 consecutive s-positions -> one 8B store
                half4 pk;
                #pragma unroll
                for (int r = 0; r < 4; ++r) pk[r] = (f16)(acc[i][j][r] + bv_);
                *(half4*)(Vt + ((long)(rowb >> 11) * 1024 + (col - 2048)) * 2048 + (rowb & 2047)) = pk;
            } else {
                #pragma unroll
                for (int r = 0; r < 4; ++r) {
                    const float val = acc[i][j][r] + bv_;
                    const int row = rowb + r;
                    if (OUT == 0)      Cf[zb * zsC + (long)row * ldc + col] = val;
                    else if (OUT == 1) Ch[zb * zsC + (long)row * ldc + col] = (f16)val;
                    else               Ch[(long)row * ldc + col] = (f16)val;
                }
            }
        }
    }
}

// ---------------------------------------------------------------------
// fused preprocessing, one dispatch:
//  blocks [0,8192):    x fp32 -> fp16
//  blocks [8192,8960): Wq/Wk/Wv [1024,1024] fp32 -> W^T fp16 [3072,1024]
//  blocks [8960,8972): bias concat -> bqkv[3072]
// ---------------------------------------------------------------------
__global__ __launch_bounds__(256)
void preproc_k(const float* __restrict__ x,
               const float* __restrict__ Wq, const float* __restrict__ Wk,
               const float* __restrict__ Wv,
               const float* __restrict__ bq, const float* __restrict__ bk,
               const float* __restrict__ bv,
               f16* __restrict__ xh, f16* __restrict__ WT, float* __restrict__ bqkv)
{
    __shared__ float tile[64][65];
    const int bx = blockIdx.x;
    const int t  = threadIdx.x;

    if (bx < 8192) {
        const long i = ((long)bx * 256 + t) * 4;
        const float4v v = *(const float4v*)(x + i);
        half4 h;
        #pragma unroll
        for (int j = 0; j < 4; ++j) h[j] = (f16)v[j];
        *(half4*)(xh + i) = h;
    } else if (bx < 8960) {
        const int f = bx - 8192;
        const int z = f >> 8;
        const int rem = f & 255;
        const int n0 = (rem & 15) * 64;
        const int k0 = (rem >> 4) * 64;
        const float* W = (z == 0) ? Wq : (z == 1) ? Wk : Wv;
        f16* T = WT + (long)z * 1048576;
        #pragma unroll
        for (int i = 0; i < 4; ++i) {
            const int r = (t >> 4) + i * 16;     // k local
            const int c = (t & 15) * 4;          // n local
            const float4v v = *(const float4v*)(W + (long)(k0 + r) * 1024 + n0 + c);
            tile[r][c + 0] = v[0]; tile[r][c + 1] = v[1];
            tile[r][c + 2] = v[2]; tile[r][c + 3] = v[3];
        }
        __syncthreads();
        #pragma unroll
        for (int i = 0; i < 4; ++i) {
            const int nr = (t >> 4) + i * 16;    // n local
            const int c  = (t & 15) * 4;         // k local
            half4 h;
            #pragma unroll
            for (int j = 0; j < 4; ++j) h[j] = (f16)tile[c + j][nr];
            *(half4*)(T + (long)(n0 + nr) * 1024 + k0 + c) = h;
        }
    } else {
        const int i = (bx - 8960) * 256 + t;
        bqkv[i] = (i < 1024) ? bq[i] : (i < 2048) ? bk[i - 1024] : bv[i - 2048];
    }
}

// ---- row softmax, in place: f16 [rows, 2048] ----
__global__ __launch_bounds__(256)
void softmax_k(f16* __restrict__ Sc)
{
    const int t = threadIdx.x;
    const long row = blockIdx.x;
    half8* p = (half8*)(Sc + row * 2048);
    const half8 hv = p[t];
    float xv[8];
    #pragma unroll
    for (int j = 0; j < 8; ++j) xv[j] = (float)hv[j];

    float m = -1e30f;
    #pragma unroll
    for (int j = 0; j < 8; ++j) m = fmaxf(m, xv[j]);
    #pragma unroll
    for (int off = 32; off; off >>= 1) m = fmaxf(m, __shfl_xor(m, off, 64));
    __shared__ float r1[4], r2[4];
    if ((t & 63) == 0) r1[t >> 6] = m;
    __syncthreads();
    m = fmaxf(fmaxf(r1[0], r1[1]), fmaxf(r1[2], r1[3]));

    float s = 0.f;
    #pragma unroll
    for (int j = 0; j < 8; ++j) { xv[j] = __expf(xv[j] - m); s += xv[j]; }
    #pragma unroll
    for (int off = 32; off; off >>= 1) s += __shfl_xor(s, off, 64);
    if ((t & 63) == 0) r2[t >> 6] = s;
    __syncthreads();
    s = r2[0] + r2[1] + r2[2] + r2[3];
    const float inv = 1.f / s;

    half8 o;
    #pragma unroll
    for (int j = 0; j < 8; ++j) o[j] = (f16)(xv[j] * inv);
    p[t] = o;
}

// ---------------------------------------------------------------------
extern "C" void kernel_launch(void* const* d_in, const int* in_sizes, int n_in,
                              void* d_out, int out_size, void* d_ws, size_t ws_size,
                              hipStream_t stream)
{
    const float* x  = (const float*)d_in[0];
    const float* Wq = (const float*)d_in[1];
    const float* bq = (const float*)d_in[2];
    const float* Wk = (const float*)d_in[3];
    const float* bk = (const float*)d_in[4];
    const float* Wv = (const float*)d_in[5];
    const float* bv = (const float*)d_in[6];
    float* out = (float*)d_out;

    char* ws = (char*)d_ws;
    const long MiB = 1024 * 1024;
    // Phase-1 temporaries (dead once the projection finishes)
    f16*   xh   = (f16*)  (ws + 0);          // 16 MiB [8192,1024]
    f16*   WT   = (f16*)  (ws + 16 * MiB);   //  6 MiB [3072,1024]
    float* bqkv = (float*)(ws + 22 * MiB);   // 12 KiB
    // Persistent / attention-phase
    f16*   scores = (f16*) (ws + 0);         // 32 MiB [4][2048][2048] f16, in-place softmax
    f16*   qk     = (f16*) (ws + 64 * MiB);  // 32 MiB [8192,2048] (q cols 0..1023, k cols 1024..2047)
    f16*   vT     = (f16*) (ws + 96 * MiB);  // 16 MiB [4][1024][2048]  -> total 112 MiB

    // 1) fused preprocessing (1 dispatch)
    preproc_k<<<8972, 256, 0, stream>>>(x, Wq, Wk, Wv, bq, bk, bv, xh, WT, bqkv);

    // 2) fused QKV projection (fp16, 256x128 blocks), V^T written directly
    gemm_k<8, 4, true><<<dim3(32, 24, 1), 256, 49152, stream>>>(
        xh, WT, bqkv, nullptr, qk, vT,
        1024, 1024, 1024, 2048, 0, 0, 0);

    // 3) attention: scores = QK^T (f16, 256x128 blocks), in-place softmax,
    //    out = P V (128x128 blocks: N=1024 needs the finer grid)
    const long SS = (long)2048 * 2048;
    gemm_k<8, 1, false><<<dim3(8, 16, 4), 256, 49152, stream>>>(
        qk, qk + 1024, nullptr, nullptr, scores, nullptr,
        1024, 2048, 2048, 2048, SS, SS, SS);
    softmax_k<<<8192, 256, 0, stream>>>(scores);
    gemm_k<4, 0, false><<<dim3(16, 8, 4), 256, 32768, stream>>>(
        scores, vT, nullptr, out, nullptr, nullptr,
        2048, 2048, 2048, 1024, SS, (long)1024 * 2048, (long)2048 * 1024);
}

// Round 9
// 253.055 us; speedup vs baseline: 1.5079x; 1.0436x over previous
//
#include <hip/hip_runtime.h>
#include <stdint.h>

typedef unsigned short ushort_t;
typedef _Float16 f16;
typedef __attribute__((ext_vector_type(8))) _Float16 half8;
typedef __attribute__((ext_vector_type(4))) _Float16 half4;
typedef __attribute__((ext_vector_type(4))) float float4v;

#define AS1 __attribute__((address_space(1)))
#define AS3 __attribute__((address_space(3)))

// async global->LDS, 16B per lane (global_load_lds_dwordx4)
static __device__ __forceinline__ void gload16(const void* g, void* l) {
    __builtin_amdgcn_global_load_lds((const AS1 unsigned int*)g,
                                     (AS3 unsigned int*)l, 16, 0, 0);
}

// raw workgroup barrier WITHOUT the vmcnt(0) drain __syncthreads implies.
// sched_barrier(0) pins memory-op motion at the barrier point (m139/m141).
static __device__ __forceinline__ void barrier_nodrain() {
    __builtin_amdgcn_sched_barrier(0);
    __builtin_amdgcn_s_barrier();
    __builtin_amdgcn_sched_barrier(0);
}

// ---------------------------------------------------------------------
// fp16 MFMA GEMM, double-buffered pipeline (AITER-style, never vmcnt(0)):
//   stage(s+1) -> buf[(s+1)&1] issued BEFORE the barrier of stage s, so its
//   global latency hides under stage s's whole compute phase. Pre-compute
//   wait is vmcnt(NLD) = "my stage(s) landed" (cheap: issued 1 iter ago).
//   Two drain-free barriers/iter fence the buffer swap.
// Wave tile IM*16 x 64; block (2*IM*16) x 128; BK=32 stages, 32-wide LDS
// rows (conflict-free, lane-contiguous for global_load_lds).
// NOTE: no LDS pointer arrays (gfx950 addrspacecast static-init bug) —
// buffers selected by offset arithmetic.
// A: [M, K] rows stride lda (fp16); B: [N, K] rows stride ldb (fp16)
// C = A*B^T (+bias[n])
// OUT: 0 = fp32 at Cf[z*zsC + row*ldc + col]
//      1 = f16  at Ch[z*zsC + row*ldc + col]
//      4 = fused QKV: col<2048 -> f16 qk[row*2048+col];
//          col>=2048 -> f16 V^T packed: Vt[(row>>11)*1024 + col-2048][row&2047]
// ---------------------------------------------------------------------
template<int IM, int OUT, bool BIAS>
__global__ __launch_bounds__(256, IM == 8 ? 2 : 4)
void gemm_k(const f16* __restrict__ A, const f16* __restrict__ B,
            const float* __restrict__ bias,
            float* __restrict__ Cf, f16* __restrict__ Ch, f16* __restrict__ Vt,
            int K, int lda, int ldb, int ldc,
            long zsA, long zsB, long zsC)
{
    constexpr int R    = IM * 32;        // block m rows (128 or 256)
    constexpr int AH   = R * 32;         // halves per A stage buffer
    constexpr int NLD  = R / 64 + 2;     // gload16 per stage (per lane)
    extern __shared__ f16 smem[];
    // layout: [A0 | A1 | B0 | B1]

    const long zb = blockIdx.z;
    A += zb * zsA; B += zb * zsB;

    const int t  = threadIdx.x;
    const int bm = blockIdx.x * R;
    const int bn = blockIdx.y * 128;

    const int  srow = t >> 2;
    const int  skg  = (t & 3) * 8;
    const f16* gA = A + (long)(bm + srow) * lda + skg;
    const f16* gB = B + (long)(bn + srow) * ldb + skg;
    const long rstepA = (long)64 * lda;
    const long rstepB = (long)64 * ldb;

    const int lane = t & 63;
    const int wv   = t >> 6;
    const int wm   = (wv & 1) * (IM * 16);
    const int wn   = (wv >> 1) * 64;
    const int lm   = lane & 15;
    const int q    = lane >> 4;

    float4v acc[IM][4];
    #pragma unroll
    for (int i = 0; i < IM; ++i)
        #pragma unroll
        for (int j = 0; j < 4; ++j)
            #pragma unroll
            for (int r = 0; r < 4; ++r) acc[i][j][r] = 0.f;

    auto stage = [&](int s) {
        const int kk  = s << 5;
        const int buf = s & 1;
        f16* dA = smem + buf * AH;
        f16* dB = smem + 2 * AH + buf * 4096;
        #pragma unroll
        for (int r = 0; r < R / 64; ++r)
            gload16(gA + kk + r * rstepA, dA + r * 2048 + t * 8);
        #pragma unroll
        for (int r = 0; r < 2; ++r)
            gload16(gB + kk + r * rstepB, dB + r * 2048 + t * 8);
    };

    const int nstage = K >> 5;
    stage(0);
    for (int s = 0; s < nstage; ++s) {
        if (s + 1 < nstage) {
            stage(s + 1);
            __builtin_amdgcn_s_waitcnt(0x0F70 | NLD);  // my stage(s) landed
        } else {
            __builtin_amdgcn_s_waitcnt(0x0F70);        // vmcnt(0), lgkm/exp skipped
        }
        barrier_nodrain();                             // all waves' stage(s) in LDS

        const int buf = s & 1;
        const f16* sA = smem + buf * AH;
        const f16* sB = smem + 2 * AH + buf * 4096;
        half8 a[IM], b[4];
        #pragma unroll
        for (int i = 0; i < IM; ++i)
            a[i] = *(const half8*)(sA + (wm + i * 16 + lm) * 32 + q * 8);
        #pragma unroll
        for (int j = 0; j < 4; ++j)
            b[j] = *(const half8*)(sB + (wn + j * 16 + lm) * 32 + q * 8);
        #pragma unroll
        for (int i = 0; i < IM; ++i)
            #pragma unroll
            for (int j = 0; j < 4; ++j)
                acc[i][j] = __builtin_amdgcn_mfma_f32_16x16x32_f16(a[i], b[j], acc[i][j], 0, 0, 0);

        barrier_nodrain();   // fence: next restage of buf[(s+1)&1] vs its readers
    }

    // epilogue; C/D layout: col = lane&15, row = (lane>>4)*4 + reg (m89/m91)
    #pragma unroll
    for (int i = 0; i < IM; ++i) {
        const int rowb = bm + wm + i * 16 + q * 4;
        #pragma unroll
        for (int j = 0; j < 4; ++j) {
            const int col = bn + wn + j * 16 + lm;
            const float bv_ = BIAS ? bias[col] : 0.f;
            if (OUT == 4 && col >= 2048) {
                // packed V^T store: 4 consecutive s-positions -> one 8B store
                half4 pk;
                #pragma unroll
                for (int r = 0; r < 4; ++r) pk[r] = (f16)(acc[i][j][r] + bv_);
                *(half4*)(Vt + ((long)(rowb >> 11) * 1024 + (col - 2048)) * 2048 + (rowb & 2047)) = pk;
            } else {
                #pragma unroll
                for (int r = 0; r < 4; ++r) {
                    const float val = acc[i][j][r] + bv_;
                    const int row = rowb + r;
                    if (OUT == 0)      Cf[zb * zsC + (long)row * ldc + col] = val;
                    else if (OUT == 1) Ch[zb * zsC + (long)row * ldc + col] = (f16)val;
                    else               Ch[(long)row * ldc + col] = (f16)val;
                }
            }
        }
    }
}

// ---------------------------------------------------------------------
// fused preprocessing, one dispatch:
//  blocks [0,8192):    x fp32 -> fp16
//  blocks [8192,8960): Wq/Wk/Wv [1024,1024] fp32 -> W^T fp16 [3072,1024]
//  blocks [8960,8972): bias concat -> bqkv[3072]
// ---------------------------------------------------------------------
__global__ __launch_bounds__(256)
void preproc_k(const float* __restrict__ x,
               const float* __restrict__ Wq, const float* __restrict__ Wk,
               const float* __restrict__ Wv,
               const float* __restrict__ bq, const float* __restrict__ bk,
               const float* __restrict__ bv,
               f16* __restrict__ xh, f16* __restrict__ WT, float* __restrict__ bqkv)
{
    __shared__ float tile[64][65];
    const int bx = blockIdx.x;
    const int t  = threadIdx.x;

    if (bx < 8192) {
        const long i = ((long)bx * 256 + t) * 4;
        const float4v v = *(const float4v*)(x + i);
        half4 h;
        #pragma unroll
        for (int j = 0; j < 4; ++j) h[j] = (f16)v[j];
        *(half4*)(xh + i) = h;
    } else if (bx < 8960) {
        const int f = bx - 8192;
        const int z = f >> 8;
        const int rem = f & 255;
        const int n0 = (rem & 15) * 64;
        const int k0 = (rem >> 4) * 64;
        const float* W = (z == 0) ? Wq : (z == 1) ? Wk : Wv;
        f16* T = WT + (long)z * 1048576;
        #pragma unroll
        for (int i = 0; i < 4; ++i) {
            const int r = (t >> 4) + i * 16;     // k local
            const int c = (t & 15) * 4;          // n local
            const float4v v = *(const float4v*)(W + (long)(k0 + r) * 1024 + n0 + c);
            tile[r][c + 0] = v[0]; tile[r][c + 1] = v[1];
            tile[r][c + 2] = v[2]; tile[r][c + 3] = v[3];
        }
        __syncthreads();
        #pragma unroll
        for (int i = 0; i < 4; ++i) {
            const int nr = (t >> 4) + i * 16;    // n local
            const int c  = (t & 15) * 4;         // k local
            half4 h;
            #pragma unroll
            for (int j = 0; j < 4; ++j) h[j] = (f16)tile[c + j][nr];
            *(half4*)(T + (long)(n0 + nr) * 1024 + k0 + c) = h;
        }
    } else {
        const int i = (bx - 8960) * 256 + t;
        bqkv[i] = (i < 1024) ? bq[i] : (i < 2048) ? bk[i - 1024] : bv[i - 2048];
    }
}

// ---- row softmax, in place: f16 [rows, 2048] ----
__global__ __launch_bounds__(256)
void softmax_k(f16* __restrict__ Sc)
{
    const int t = threadIdx.x;
    const long row = blockIdx.x;
    half8* p = (half8*)(Sc + row * 2048);
    const half8 hv = p[t];
    float xv[8];
    #pragma unroll
    for (int j = 0; j < 8; ++j) xv[j] = (float)hv[j];

    float m = -1e30f;
    #pragma unroll
    for (int j = 0; j < 8; ++j) m = fmaxf(m, xv[j]);
    #pragma unroll
    for (int off = 32; off; off >>= 1) m = fmaxf(m, __shfl_xor(m, off, 64));
    __shared__ float r1[4], r2[4];
    if ((t & 63) == 0) r1[t >> 6] = m;
    __syncthreads();
    m = fmaxf(fmaxf(r1[0], r1[1]), fmaxf(r1[2], r1[3]));

    float s = 0.f;
    #pragma unroll
    for (int j = 0; j < 8; ++j) { xv[j] = __expf(xv[j] - m); s += xv[j]; }
    #pragma unroll
    for (int off = 32; off; off >>= 1) s += __shfl_xor(s, off, 64);
    if ((t & 63) == 0) r2[t >> 6] = s;
    __syncthreads();
    s = r2[0] + r2[1] + r2[2] + r2[3];
    const float inv = 1.f / s;

    half8 o;
    #pragma unroll
    for (int j = 0; j < 8; ++j) o[j] = (f16)(xv[j] * inv);
    p[t] = o;
}

// ---------------------------------------------------------------------
extern "C" void kernel_launch(void* const* d_in, const int* in_sizes, int n_in,
                              void* d_out, int out_size, void* d_ws, size_t ws_size,
                              hipStream_t stream)
{
    const float* x  = (const float*)d_in[0];
    const float* Wq = (const float*)d_in[1];
    const float* bq = (const float*)d_in[2];
    const float* Wk = (const float*)d_in[3];
    const float* bk = (const float*)d_in[4];
    const float* Wv = (const float*)d_in[5];
    const float* bv = (const float*)d_in[6];
    float* out = (float*)d_out;

    char* ws = (char*)d_ws;
    const long MiB = 1024 * 1024;
    // Phase-1 temporaries (dead once the projection finishes)
    f16*   xh   = (f16*)  (ws + 0);          // 16 MiB [8192,1024]
    f16*   WT   = (f16*)  (ws + 16 * MiB);   //  6 MiB [3072,1024]
    float* bqkv = (float*)(ws + 22 * MiB);   // 12 KiB
    // Persistent / attention-phase
    f16*   scores = (f16*) (ws + 0);         // 32 MiB [4][2048][2048] f16, in-place softmax
    f16*   qk     = (f16*) (ws + 64 * MiB);  // 32 MiB [8192,2048] (q cols 0..1023, k cols 1024..2047)
    f16*   vT     = (f16*) (ws + 96 * MiB);  // 16 MiB [4][1024][2048]  -> total 112 MiB

    // 1) fused preprocessing (1 dispatch)
    preproc_k<<<8972, 256, 0, stream>>>(x, Wq, Wk, Wv, bq, bk, bv, xh, WT, bqkv);

    // 2) fused QKV projection (fp16, 256x128 blocks, dbuf pipeline)
    gemm_k<8, 4, true><<<dim3(32, 24, 1), 256, 49152, stream>>>(
        xh, WT, bqkv, nullptr, qk, vT,
        1024, 1024, 1024, 2048, 0, 0, 0);

    // 3) attention: scores = QK^T (f16), in-place softmax, out = P V
    const long SS = (long)2048 * 2048;
    gemm_k<8, 1, false><<<dim3(8, 16, 4), 256, 49152, stream>>>(
        qk, qk + 1024, nullptr, nullptr, scores, nullptr,
        1024, 2048, 2048, 2048, SS, SS, SS);
    softmax_k<<<8192, 256, 0, stream>>>(scores);
    gemm_k<4, 0, false><<<dim3(16, 8, 4), 256, 32768, stream>>>(
        scores, vT, nullptr, out, nullptr, nullptr,
        2048, 2048, 2048, 1024, SS, (long)1024 * 2048, (long)2048 * 1024);
}